// Round 3
// baseline (654.129 us; speedup 1.0000x reference)
//
#include <hip/hip_runtime.h>
#include <math.h>

#define SEQ 256
#define BATCH 512
#define IN_DIM 512
#define HID 512
#define NQ 32

typedef float v2f __attribute__((ext_vector_type(2)));

__device__ __forceinline__ float fast_rcp(float x) { return __builtin_amdgcn_rcpf(x); }

__device__ __forceinline__ float tanh_fast(float x) {
    // tanh(x) = sign(x) * (1 - e) / (1 + e),  e = exp(-2|x|)  (never overflows)
    float a = fabsf(x);
    float e = __expf(-2.0f * a);
    float r = (1.0f - e) * fast_rcp(1.0f + e);
    return copysignf(r, x);
}

// ---------------------------------------------------------------------------
// Phase 1: Xp[row][nq] = fc_b[nq] + sum_k inputs[row][k] * fc_w[nq][k]
// 8192 blocks x 256 threads; 16 rows per block in LDS (32 KB) -> 4 blocks/CU
// (__launch_bounds__(256,4), VGPR cap 128). 2 rows per iteration so the two
// 5-deep shfl-reduce chains overlap (ILP). pk-FMA via float2 ext-vector.
// ---------------------------------------------------------------------------
__global__ __launch_bounds__(256, 4) void xp_kernel(const float* __restrict__ x,
                                                    const float* __restrict__ fc_w,
                                                    const float* __restrict__ fc_b,
                                                    float* __restrict__ xp) {
    const int tid = threadIdx.x;
    const int g2 = tid >> 5;  // nq group: owns nq 4*g2 .. 4*g2+3
    const int s  = tid & 31;  // k-split lane: k = 4s..4s+3 (+128j)

    __shared__ float4 tile4[16 * 128];  // 16 rows x 512 floats = 32 KB

    v2f wlo[4][4], whi[4][4];
#pragma unroll
    for (int i = 0; i < 4; ++i) {
        const float* wr = fc_w + (size_t)(g2 * 4 + i) * (IN_DIM + HID);
#pragma unroll
        for (int j = 0; j < 4; ++j) {
            float4 v = *reinterpret_cast<const float4*>(wr + 4 * s + 128 * j);
            wlo[i][j] = (v2f){v.x, v.y};
            whi[i][j] = (v2f){v.z, v.w};
        }
    }
    const float4 bias4 = reinterpret_cast<const float4*>(fc_b)[g2];

    const float4* x4 = reinterpret_cast<const float4*>(x) + (size_t)blockIdx.x * (16 * 128);
#pragma unroll
    for (int q = 0; q < 8; ++q)
        tile4[tid + 256 * q] = x4[tid + 256 * q];
    __syncthreads();

    const int row0 = blockIdx.x * 16;
    float4* xp4 = reinterpret_cast<float4*>(xp);
    for (int rp = 0; rp < 8; ++rp) {
        v2f aA[4], aB[4];
#pragma unroll
        for (int i = 0; i < 4; ++i) { aA[i] = (v2f){0.f, 0.f}; aB[i] = (v2f){0.f, 0.f}; }
#pragma unroll
        for (int j = 0; j < 4; ++j) {
            float4 hA = tile4[(2 * rp) * 128 + s + 32 * j];
            float4 hB = tile4[(2 * rp + 1) * 128 + s + 32 * j];
            v2f hAlo = (v2f){hA.x, hA.y}, hAhi = (v2f){hA.z, hA.w};
            v2f hBlo = (v2f){hB.x, hB.y}, hBhi = (v2f){hB.z, hB.w};
#pragma unroll
            for (int i = 0; i < 4; ++i) {
                aA[i] = __builtin_elementwise_fma(hAlo, wlo[i][j], aA[i]);
                aA[i] = __builtin_elementwise_fma(hAhi, whi[i][j], aA[i]);
                aB[i] = __builtin_elementwise_fma(hBlo, wlo[i][j], aB[i]);
                aB[i] = __builtin_elementwise_fma(hBhi, whi[i][j], aB[i]);
            }
        }
        float rA[4], rB[4];
#pragma unroll
        for (int i = 0; i < 4; ++i) { rA[i] = aA[i].x + aA[i].y; rB[i] = aB[i].x + aB[i].y; }
#pragma unroll
        for (int m = 1; m <= 16; m <<= 1) {
#pragma unroll
            for (int i = 0; i < 4; ++i) {
                rA[i] += __shfl_xor(rA[i], m);
                rB[i] += __shfl_xor(rB[i], m);
            }
        }
        if (s == 0) {
            xp4[(size_t)(row0 + 2 * rp) * 8 + g2] =
                make_float4(rA[0] + bias4.x, rA[1] + bias4.y, rA[2] + bias4.z, rA[3] + bias4.w);
            xp4[(size_t)(row0 + 2 * rp + 1) * 8 + g2] =
                make_float4(rB[0] + bias4.x, rB[1] + bias4.y, rB[2] + bias4.z, rB[3] + bias4.w);
        }
    }
}

// ---------------------------------------------------------------------------
// Phase 2: per-batch recurrence. 512 blocks x 512 threads (8 waves), 1 batch
// per block, 2 blocks/CU -> 4 waves/SIMD (round-2 was 2/SIMD, 39% packed).
// Two barriers per step (round-2 had three):
//   A: h-GEMV. g=tid>>4 owns nq g; s=tid&15 covers k=4s+64j (+0..3).
//      16-lane shfl reduce -> qin_s.  [barrier 1]
//   B: per-wave REDUNDANT scan (no barrier): every wave reads qin_s, does the
//      cos+cumprod scan on its two 32-lane halves; lanes<32 produce sigmoid,
//      lanes>=32 produce tanh; writes interleaved (sig[q],th[q]) pairs into a
//      per-wave LDS scratch; in-wave s_waitcnt lgkmcnt(0) orders RAW.
//   C: thread owns hid=tid: f/g via 32 pk-FMA on (sig,th) float2 pairs,
//      state update, write hbuf[p^1] + out.  [barrier 2]
// xp[:,b,:] staged in LDS once (32 KB) to keep global loads out of the chain.
// ---------------------------------------------------------------------------
__global__ __launch_bounds__(512, 4) void rnn_kernel(const float* __restrict__ xp,
                                                     const float* __restrict__ fc_w,
                                                     const float* __restrict__ out_w,
                                                     const float* __restrict__ out_b,
                                                     float* __restrict__ out) {
    const int b = blockIdx.x;
    const int tid = threadIdx.x;
    const int g = tid >> 4;     // 0..31 : nq owned in Phase A
    const int s = tid & 15;     // 0..15 : k lane
    const int w = tid >> 6;     // wave id 0..7
    const int lane = tid & 63;
    const int l31 = lane & 31;

    __shared__ float hbuf[2][HID];                  // 4 KB (double-buffered h)
    __shared__ float qin_s[NQ];
    __shared__ __align__(16) float wbuf[8][64];     // per-wave (sig,th) pairs, 2 KB
    __shared__ __align__(16) float xps[SEQ * NQ];   // 32 KB

    // Wh fragment: k = 4s + 64j + {0..3}
    v2f wh_lo[8], wh_hi[8];
    {
        const float* wr = fc_w + (size_t)g * (IN_DIM + HID) + IN_DIM + 4 * s;
#pragma unroll
        for (int j = 0; j < 8; ++j) {
            float4 v = *reinterpret_cast<const float4*>(wr + 64 * j);
            wh_lo[j] = (v2f){v.x, v.y};
            wh_hi[j] = (v2f){v.z, v.w};
        }
    }
    // out_w row for hid = tid
    float ow[NQ];
    {
        const float4* owr = reinterpret_cast<const float4*>(out_w + (size_t)tid * NQ);
#pragma unroll
        for (int q4 = 0; q4 < 8; ++q4) {
            float4 v = owr[q4];
            ow[4 * q4 + 0] = v.x; ow[4 * q4 + 1] = v.y;
            ow[4 * q4 + 2] = v.z; ow[4 * q4 + 3] = v.w;
        }
    }
    const float ob = out_b[tid];

    // stage xp[:, b, :] -> LDS (coalesced-ish: 8 consecutive threads per row)
    {
        const float4* xpg = reinterpret_cast<const float4*>(xp);
        float4* xps4 = reinterpret_cast<float4*>(xps);
#pragma unroll
        for (int k = 0; k < 4; ++k) {
            int idx = tid + 512 * k;          // 0..2047
            int t = idx >> 3, q4 = idx & 7;
            xps4[idx] = xpg[((size_t)t * BATCH + b) * 8 + q4];
        }
    }
    hbuf[0][tid] = 0.0f;
    float c = 0.0f;
    __syncthreads();

    float* hx_out = out + (size_t)SEQ * BATCH * HID + (size_t)b * HID;
    float* cx_out = hx_out + (size_t)BATCH * HID;

    int p = 0;
    for (int t = 0; t < SEQ; ++t) {
        // ---- Phase A: q_in = Xp[t,b,:] + h @ Wh.T -------------------------
        const float4* h4 = reinterpret_cast<const float4*>(hbuf[p]);
        v2f a2 = (v2f){0.f, 0.f};
#pragma unroll
        for (int j = 0; j < 8; ++j) {
            float4 hv = h4[s + 16 * j];
            a2 = __builtin_elementwise_fma((v2f){hv.x, hv.y}, wh_lo[j], a2);
            a2 = __builtin_elementwise_fma((v2f){hv.z, hv.w}, wh_hi[j], a2);
        }
        float a = a2.x + a2.y;
        a += __shfl_xor(a, 1);
        a += __shfl_xor(a, 2);
        a += __shfl_xor(a, 4);
        a += __shfl_xor(a, 8);
        if (s == 0) qin_s[g] = a + xps[t * NQ + g];
        __syncthreads();                     // barrier 1: qin_s ready

        // ---- Phase B: per-wave redundant scan + activations ---------------
        {
            float q = qin_s[l31];
            float pp = __cosf(q);
#pragma unroll
            for (int off = 1; off <= 16; off <<= 1) {
                float up = __shfl_up(pp, off, 32);
                if (l31 >= off) pp *= up;
            }
            // pp in [-1,1] (product of cosines) -> exp args bounded, no overflow
            float arg = (lane < 32) ? -pp : (-2.0f * pp);
            float e = __expf(arg);
            float num = (lane < 32) ? 1.0f : (1.0f - e);
            float val = num * fast_rcp(1.0f + e);   // sigmoid | tanh
            wbuf[w][(l31 << 1) | (lane >> 5)] = val; // sig at 2q, th at 2q+1
        }
        asm volatile("s_waitcnt lgkmcnt(0)" ::: "memory");  // in-wave RAW fence

        // ---- Phase C: f/g via pk-FMA + state update -----------------------
        const float4* st4 = reinterpret_cast<const float4*>(wbuf[w]);
        v2f acc = (v2f){ob, ob};             // (f, g)
#pragma unroll
        for (int m = 0; m < 16; ++m) {
            float4 v = st4[m];               // (sig[2m], th[2m], sig[2m+1], th[2m+1])
            acc = __builtin_elementwise_fma((v2f){v.x, v.y}, (v2f){ow[2 * m], ow[2 * m]}, acc);
            acc = __builtin_elementwise_fma((v2f){v.z, v.w}, (v2f){ow[2 * m + 1], ow[2 * m + 1]}, acc);
        }
        float f = acc.x, gg = acc.y;
        c = f * (c + gg);                    // f*c + i*g with i == f
        float h = f * tanh_fast(c);          // o == f

        hbuf[p ^ 1][tid] = h;
        out[((size_t)t * BATCH + b) * HID + tid] = h;
        if (t == SEQ - 1) { hx_out[tid] = h; cx_out[tid] = c; }
        __syncthreads();                     // barrier 2: hbuf[p^1] ready
        p ^= 1;
    }
}

extern "C" void kernel_launch(void* const* d_in, const int* in_sizes, int n_in,
                              void* d_out, int out_size, void* d_ws, size_t ws_size,
                              hipStream_t stream) {
    const float* inputs = (const float*)d_in[0];
    const float* fc_w   = (const float*)d_in[1];
    const float* fc_b   = (const float*)d_in[2];
    const float* out_w  = (const float*)d_in[3];
    const float* out_b  = (const float*)d_in[4];
    float* out = (float*)d_out;
    float* xp  = (float*)d_ws;   // SEQ*BATCH*NQ floats = 16.8 MB

    xp_kernel<<<(SEQ * BATCH) / 16, 256, 0, stream>>>(inputs, fc_w, fc_b, xp);
    rnn_kernel<<<BATCH, 512, 0, stream>>>(xp, fc_w, out_w, out_b, out);
}

// Round 4
// 509.197 us; speedup vs baseline: 1.2846x; 1.2846x over previous
//
#include <hip/hip_runtime.h>
#include <math.h>

#define SEQ 256
#define BATCH 512
#define IN_DIM 512
#define HID 512
#define NQ 32

typedef float v2f __attribute__((ext_vector_type(2)));

__device__ __forceinline__ float fast_rcp(float x) { return __builtin_amdgcn_rcpf(x); }

__device__ __forceinline__ float tanh_fast(float x) {
    // tanh(x) = sign(x) * (1 - e) / (1 + e),  e = exp(-2|x|)  (never overflows)
    float a = fabsf(x);
    float e = __expf(-2.0f * a);
    float r = (1.0f - e) * fast_rcp(1.0f + e);
    return copysignf(r, x);
}

// ---------------------------------------------------------------------------
// Phase 1: Xp[row][nq] = fc_b[nq] + sum_k inputs[row][k] * fc_w[nq][k]
// 8192 blocks x 256 threads; 16 rows per block in LDS (32 KB) -> 4 blocks/CU.
// Unchanged from round 3 (measured ~74 us).
// ---------------------------------------------------------------------------
__global__ __launch_bounds__(256, 4) void xp_kernel(const float* __restrict__ x,
                                                    const float* __restrict__ fc_w,
                                                    const float* __restrict__ fc_b,
                                                    float* __restrict__ xp) {
    const int tid = threadIdx.x;
    const int g2 = tid >> 5;  // nq group: owns nq 4*g2 .. 4*g2+3
    const int s  = tid & 31;  // k-split lane: k = 4s..4s+3 (+128j)

    __shared__ float4 tile4[16 * 128];  // 16 rows x 512 floats = 32 KB

    v2f wlo[4][4], whi[4][4];
#pragma unroll
    for (int i = 0; i < 4; ++i) {
        const float* wr = fc_w + (size_t)(g2 * 4 + i) * (IN_DIM + HID);
#pragma unroll
        for (int j = 0; j < 4; ++j) {
            float4 v = *reinterpret_cast<const float4*>(wr + 4 * s + 128 * j);
            wlo[i][j] = (v2f){v.x, v.y};
            whi[i][j] = (v2f){v.z, v.w};
        }
    }
    const float4 bias4 = reinterpret_cast<const float4*>(fc_b)[g2];

    const float4* x4 = reinterpret_cast<const float4*>(x) + (size_t)blockIdx.x * (16 * 128);
#pragma unroll
    for (int q = 0; q < 8; ++q)
        tile4[tid + 256 * q] = x4[tid + 256 * q];
    __syncthreads();

    const int row0 = blockIdx.x * 16;
    float4* xp4 = reinterpret_cast<float4*>(xp);
    for (int rp = 0; rp < 8; ++rp) {
        v2f aA[4], aB[4];
#pragma unroll
        for (int i = 0; i < 4; ++i) { aA[i] = (v2f){0.f, 0.f}; aB[i] = (v2f){0.f, 0.f}; }
#pragma unroll
        for (int j = 0; j < 4; ++j) {
            float4 hA = tile4[(2 * rp) * 128 + s + 32 * j];
            float4 hB = tile4[(2 * rp + 1) * 128 + s + 32 * j];
            v2f hAlo = (v2f){hA.x, hA.y}, hAhi = (v2f){hA.z, hA.w};
            v2f hBlo = (v2f){hB.x, hB.y}, hBhi = (v2f){hB.z, hB.w};
#pragma unroll
            for (int i = 0; i < 4; ++i) {
                aA[i] = __builtin_elementwise_fma(hAlo, wlo[i][j], aA[i]);
                aA[i] = __builtin_elementwise_fma(hAhi, whi[i][j], aA[i]);
                aB[i] = __builtin_elementwise_fma(hBlo, wlo[i][j], aB[i]);
                aB[i] = __builtin_elementwise_fma(hBhi, whi[i][j], aB[i]);
            }
        }
        float rA[4], rB[4];
#pragma unroll
        for (int i = 0; i < 4; ++i) { rA[i] = aA[i].x + aA[i].y; rB[i] = aB[i].x + aB[i].y; }
#pragma unroll
        for (int m = 1; m <= 16; m <<= 1) {
#pragma unroll
            for (int i = 0; i < 4; ++i) {
                rA[i] += __shfl_xor(rA[i], m);
                rB[i] += __shfl_xor(rB[i], m);
            }
        }
        if (s == 0) {
            xp4[(size_t)(row0 + 2 * rp) * 8 + g2] =
                make_float4(rA[0] + bias4.x, rA[1] + bias4.y, rA[2] + bias4.z, rA[3] + bias4.w);
            xp4[(size_t)(row0 + 2 * rp + 1) * 8 + g2] =
                make_float4(rB[0] + bias4.x, rB[1] + bias4.y, rB[2] + bias4.z, rB[3] + bias4.w);
        }
    }
}

// ---------------------------------------------------------------------------
// Phase 2: per-batch recurrence. 512 blocks x 256 threads (4 waves), 1 batch
// per block, __launch_bounds__(256,2) -- round-2's proven register shape
// (124 VGPR, no spill). Round-3's (512,4) squeezed VGPR to 64 -> weight
// spills in the serial chain -> regression. Do NOT raise wave count.
// Two barriers per step:
//   A: h-GEMV, pk-FMA. g=tid>>5 owns nq 4g..4g+3; s=tid&31, k=4s+128j+{0..3}.
//      float4 LDS reads of h, 32 v_pk_fma, 32-lane shfl reduce. [barrier 1]
//   B: per-wave REDUNDANT scan (no barrier): all 4 waves read qin_s, do the
//      cos+cumprod scan on their two 32-lane halves; lanes<32 -> sigmoid,
//      lanes>=32 -> tanh; write interleaved (sig,th) pairs to per-wave wbuf;
//      in-wave s_waitcnt lgkmcnt(0) + sched_barrier orders the RAW.
//   C: thread owns hid=tid,tid+256: f/g via 64 v_pk_fma on (sig,th) float2
//      pairs against broadcast ow scalars; state update. [barrier 2]
// xp[:,b,:] staged once in LDS (32 KB). Total LDS 37.3 KB (<80 KB @ 2/CU).
// ---------------------------------------------------------------------------
__global__ __launch_bounds__(256, 2) void rnn_kernel(const float* __restrict__ xp,
                                                     const float* __restrict__ fc_w,
                                                     const float* __restrict__ out_w,
                                                     const float* __restrict__ out_b,
                                                     float* __restrict__ out) {
    const int b = blockIdx.x;
    const int tid = threadIdx.x;
    const int g = tid >> 5;     // 0..7 : nq group (owns nq 4g..4g+3)
    const int s = tid & 31;     // 0..31: k lane
    const int w4 = tid >> 6;    // wave id 0..3
    const int lane = tid & 63;
    const int l31 = lane & 31;

    __shared__ __align__(16) float hbuf[2][HID];     // 4 KB double-buffered h
    __shared__ __align__(16) float qin_s[NQ];
    __shared__ __align__(16) float wbuf[4][64];      // per-wave (sig,th) pairs
    __shared__ __align__(16) float xps[SEQ * NQ];    // 32 KB

    // Wh fragment: wh_{lo,hi}[i][j] = fc_w[4g+i][512 + 4s + 128j + {0,1}/{2,3}]
    v2f wh_lo[4][4], wh_hi[4][4];
#pragma unroll
    for (int i = 0; i < 4; ++i) {
        const float* wr = fc_w + (size_t)(g * 4 + i) * (IN_DIM + HID) + IN_DIM + 4 * s;
#pragma unroll
        for (int j = 0; j < 4; ++j) {
            float4 v = *reinterpret_cast<const float4*>(wr + 128 * j);
            wh_lo[i][j] = (v2f){v.x, v.y};
            wh_hi[i][j] = (v2f){v.z, v.w};
        }
    }
    // out_w rows for hid = tid and tid+256
    float ow0[NQ], ow1[NQ];
    {
        const float4* o0 = reinterpret_cast<const float4*>(out_w + (size_t)tid * NQ);
        const float4* o1 = reinterpret_cast<const float4*>(out_w + (size_t)(tid + 256) * NQ);
#pragma unroll
        for (int q4 = 0; q4 < 8; ++q4) {
            float4 a = o0[q4], bq = o1[q4];
            ow0[4 * q4 + 0] = a.x;  ow0[4 * q4 + 1] = a.y;
            ow0[4 * q4 + 2] = a.z;  ow0[4 * q4 + 3] = a.w;
            ow1[4 * q4 + 0] = bq.x; ow1[4 * q4 + 1] = bq.y;
            ow1[4 * q4 + 2] = bq.z; ow1[4 * q4 + 3] = bq.w;
        }
    }
    const float ob0 = out_b[tid];
    const float ob1 = out_b[tid + 256];

    // stage xp[:, b, :] -> LDS once
    {
        const float4* xpg = reinterpret_cast<const float4*>(xp);
        float4* xps4 = reinterpret_cast<float4*>(xps);
#pragma unroll
        for (int k = 0; k < 8; ++k) {
            int idx = tid + 256 * k;          // 0..2047
            int t = idx >> 3, q4 = idx & 7;
            xps4[idx] = xpg[((size_t)t * BATCH + b) * 8 + q4];
        }
    }
    hbuf[0][tid] = 0.0f;
    hbuf[0][tid + 256] = 0.0f;
    float c0 = 0.0f, c1 = 0.0f;
    __syncthreads();

    float* hx_out = out + (size_t)SEQ * BATCH * HID + (size_t)b * HID;
    float* cx_out = hx_out + (size_t)BATCH * HID;

    int p = 0;
    for (int t = 0; t < SEQ; ++t) {
        // ---- Phase A: q_in = Xp[t,b,:] + h @ Wh.T (pk-FMA) ----------------
        const float4* h4 = reinterpret_cast<const float4*>(hbuf[p]);
        v2f acc[4];
#pragma unroll
        for (int i = 0; i < 4; ++i) acc[i] = (v2f){0.f, 0.f};
#pragma unroll
        for (int j = 0; j < 4; ++j) {
            float4 hv = h4[s + 32 * j];       // h[4s+128j .. +3]
            v2f hlo = (v2f){hv.x, hv.y}, hhi = (v2f){hv.z, hv.w};
#pragma unroll
            for (int i = 0; i < 4; ++i) {
                acc[i] = __builtin_elementwise_fma(hlo, wh_lo[i][j], acc[i]);
                acc[i] = __builtin_elementwise_fma(hhi, wh_hi[i][j], acc[i]);
            }
        }
        float r[4];
#pragma unroll
        for (int i = 0; i < 4; ++i) r[i] = acc[i].x + acc[i].y;
#pragma unroll
        for (int m = 1; m <= 16; m <<= 1) {
#pragma unroll
            for (int i = 0; i < 4; ++i) r[i] += __shfl_xor(r[i], m);
        }
        if (s == 0) {
            const float4 xq = reinterpret_cast<const float4*>(xps)[t * 8 + g];
            reinterpret_cast<float4*>(qin_s)[g] =
                make_float4(r[0] + xq.x, r[1] + xq.y, r[2] + xq.z, r[3] + xq.w);
        }
        __syncthreads();                     // barrier 1: qin_s ready

        // ---- Phase B: per-wave redundant scan + activations ---------------
        {
            float q = qin_s[l31];
            float pp = __cosf(q);
#pragma unroll
            for (int off = 1; off <= 16; off <<= 1) {
                float up = __shfl_up(pp, off, 32);
                if (l31 >= off) pp *= up;
            }
            // pp in [-1,1] (product of cosines) -> exp args bounded
            float arg = (lane < 32) ? -pp : (-2.0f * pp);
            float e = __expf(arg);
            float num = (lane < 32) ? 1.0f : (1.0f - e);
            float val = num * fast_rcp(1.0f + e);     // sigmoid | tanh
            wbuf[w4][(l31 << 1) | (lane >> 5)] = val; // sig at 2q, th at 2q+1
        }
        asm volatile("s_waitcnt lgkmcnt(0)" ::: "memory");  // in-wave RAW fence
        __builtin_amdgcn_sched_barrier(0);

        // ---- Phase C: f/g via pk-FMA + state update -----------------------
        const float4* st4 = reinterpret_cast<const float4*>(wbuf[w4]);
        v2f a0 = (v2f){ob0, ob0};            // (f0, g0)
        v2f a1 = (v2f){ob1, ob1};            // (f1, g1)
#pragma unroll
        for (int m = 0; m < 16; ++m) {
            float4 v = st4[m];               // (sig[2m], th[2m], sig[2m+1], th[2m+1])
            v2f plo = (v2f){v.x, v.y}, phi = (v2f){v.z, v.w};
            a0 = __builtin_elementwise_fma(plo, (v2f){ow0[2 * m], ow0[2 * m]}, a0);
            a0 = __builtin_elementwise_fma(phi, (v2f){ow0[2 * m + 1], ow0[2 * m + 1]}, a0);
            a1 = __builtin_elementwise_fma(plo, (v2f){ow1[2 * m], ow1[2 * m]}, a1);
            a1 = __builtin_elementwise_fma(phi, (v2f){ow1[2 * m + 1], ow1[2 * m + 1]}, a1);
        }
        float f0 = a0.x, g0 = a0.y, f1 = a1.x, g1 = a1.y;
        c0 = f0 * (c0 + g0);                 // f*c + i*g with i == f
        c1 = f1 * (c1 + g1);
        float h0 = f0 * tanh_fast(c0);       // o == f
        float h1 = f1 * tanh_fast(c1);

        hbuf[p ^ 1][tid] = h0;
        hbuf[p ^ 1][tid + 256] = h1;
        float* orow = out + ((size_t)t * BATCH + b) * HID;
        orow[tid] = h0;
        orow[tid + 256] = h1;
        if (t == SEQ - 1) {
            hx_out[tid] = h0; hx_out[tid + 256] = h1;
            cx_out[tid] = c0; cx_out[tid + 256] = c1;
        }
        __syncthreads();                     // barrier 2: hbuf[p^1] ready
        p ^= 1;
    }
}

extern "C" void kernel_launch(void* const* d_in, const int* in_sizes, int n_in,
                              void* d_out, int out_size, void* d_ws, size_t ws_size,
                              hipStream_t stream) {
    const float* inputs = (const float*)d_in[0];
    const float* fc_w   = (const float*)d_in[1];
    const float* fc_b   = (const float*)d_in[2];
    const float* out_w  = (const float*)d_in[3];
    const float* out_b  = (const float*)d_in[4];
    float* out = (float*)d_out;
    float* xp  = (float*)d_ws;   // SEQ*BATCH*NQ floats = 16.8 MB

    xp_kernel<<<(SEQ * BATCH) / 16, 256, 0, stream>>>(inputs, fc_w, fc_b, xp);
    rnn_kernel<<<BATCH, 256, 0, stream>>>(xp, fc_w, out_w, out_b, out);
}

// Round 6
// 378.805 us; speedup vs baseline: 1.7268x; 1.3442x over previous
//
#include <hip/hip_runtime.h>
#include <math.h>

#define SEQ 256
#define BATCH 512
#define IN_DIM 512
#define HID 512
#define NQ 32

typedef float v2f __attribute__((ext_vector_type(2)));

__device__ __forceinline__ float fast_rcp(float x) { return __builtin_amdgcn_rcpf(x); }

__device__ __forceinline__ float tanh_fast(float x) {
    // tanh(x) = sign(x) * (1 - e) / (1 + e),  e = exp(-2|x|)  (never overflows)
    float a = fabsf(x);
    float e = __expf(-2.0f * a);
    float r = (1.0f - e) * fast_rcp(1.0f + e);
    return copysignf(r, x);
}

// ---- DPP cross-lane helpers (VALU-speed; replaces ds_bpermute shuffles) ----
// __builtin_amdgcn_update_dpp needs CONSTANT ctrl/mask args -> template them.
template <int CTRL>
__device__ __forceinline__ float dpp_add(float x) {
    int t = __builtin_amdgcn_update_dpp(0, __float_as_int(x), CTRL, 0xF, 0xF, false);
    return x + __int_as_float(t);
}
// Sum over each 16-lane row. After xor1+xor2 all quads are uniform, so
// half_mirror (lane^7) adds the other quad and mirror (lane^15) the other 8.
__device__ __forceinline__ float reduce16_add(float x) {
    x = dpp_add<0xB1>(x);   // quad_perm [1,0,3,2] : xor1
    x = dpp_add<0x4E>(x);   // quad_perm [2,3,0,1] : xor2
    x = dpp_add<0x141>(x);  // row_half_mirror     : xor4 equivalent
    x = dpp_add<0x140>(x);  // row_mirror          : xor8 equivalent
    return x;
}
template <int CTRL, int ROW_MASK>
__device__ __forceinline__ float dpp_mul1(float x) {
    int t = __builtin_amdgcn_update_dpp(0x3f800000 /*1.0f*/, __float_as_int(x),
                                        CTRL, ROW_MASK, 0xF, false);
    return x * __int_as_float(t);
}
// Inclusive cumprod within each 32-lane half of the wave.
// row_shr never crosses 16-lane rows; bcast15 is masked to odd rows ONLY
// (row_mask=0xA) so lane31 cannot leak into the lanes>=32 half.
__device__ __forceinline__ float scan32_mul(float x) {
    x = dpp_mul1<0x111, 0xF>(x);  // row_shr:1
    x = dpp_mul1<0x112, 0xF>(x);  // row_shr:2
    x = dpp_mul1<0x114, 0xF>(x);  // row_shr:4
    x = dpp_mul1<0x118, 0xF>(x);  // row_shr:8
    x = dpp_mul1<0x142, 0xA>(x);  // row_bcast:15 into odd rows
    return x;
}

// ---------------------------------------------------------------------------
// Phase 1: Xp[row][nq] = fc_b[nq] + sum_k inputs[row][k] * fc_w[nq][k]
// 8192 blocks x 256 threads; 16 rows/block in LDS (32 KB), 4 blocks/CU.
// Thread (g2=tid>>4, s=tid&15): owns nq {2g2, 2g2+1}, k = 4s+64j, j=0..7.
// Reduce over the 16 s-lanes is pure DPP (round-4 used 20 ds_bpermute per
// row-pair). 2 rows per iter for ILP.
// ---------------------------------------------------------------------------
__global__ __launch_bounds__(256, 4) void xp_kernel(const float* __restrict__ x,
                                                    const float* __restrict__ fc_w,
                                                    const float* __restrict__ fc_b,
                                                    float* __restrict__ xp) {
    const int tid = threadIdx.x;
    const int g2 = tid >> 4;  // 0..15 : owns nq {2g2, 2g2+1}
    const int s  = tid & 15;  // k lane: k = 4s + 64j

    __shared__ float4 tile4[16 * 128];  // 16 rows x 512 floats = 32 KB

    // weights: w{A,B}_{lo,hi}[j] = fc_w[2g2+{0,1}][4s+64j + {0,1}/{2,3}]
    v2f wA_lo[8], wA_hi[8], wB_lo[8], wB_hi[8];
    {
        const float* wrA = fc_w + (size_t)(g2 * 2 + 0) * (IN_DIM + HID) + 4 * s;
        const float* wrB = fc_w + (size_t)(g2 * 2 + 1) * (IN_DIM + HID) + 4 * s;
#pragma unroll
        for (int j = 0; j < 8; ++j) {
            float4 a = *reinterpret_cast<const float4*>(wrA + 64 * j);
            float4 b = *reinterpret_cast<const float4*>(wrB + 64 * j);
            wA_lo[j] = (v2f){a.x, a.y}; wA_hi[j] = (v2f){a.z, a.w};
            wB_lo[j] = (v2f){b.x, b.y}; wB_hi[j] = (v2f){b.z, b.w};
        }
    }
    const float2 bias2 = reinterpret_cast<const float2*>(fc_b)[g2];

    const float4* x4 = reinterpret_cast<const float4*>(x) + (size_t)blockIdx.x * (16 * 128);
#pragma unroll
    for (int q = 0; q < 8; ++q)
        tile4[tid + 256 * q] = x4[tid + 256 * q];
    __syncthreads();

    const int row0 = blockIdx.x * 16;
    float2* xp2 = reinterpret_cast<float2*>(xp);
    for (int rp = 0; rp < 8; ++rp) {
        const int r0 = 2 * rp, r1 = 2 * rp + 1;
        v2f aA0 = (v2f){0.f, 0.f}, aA1 = aA0, aB0 = aA0, aB1 = aA0;
        v2f bA0 = aA0, bA1 = aA0, bB0 = aA0, bB1 = aA0;  // j-parity split (ILP)
#pragma unroll
        for (int j = 0; j < 8; j += 2) {
            float4 h0 = tile4[r0 * 128 + s + 16 * j];
            float4 h1 = tile4[r1 * 128 + s + 16 * j];
            v2f h0lo = (v2f){h0.x, h0.y}, h0hi = (v2f){h0.z, h0.w};
            v2f h1lo = (v2f){h1.x, h1.y}, h1hi = (v2f){h1.z, h1.w};
            aA0 = __builtin_elementwise_fma(h0lo, wA_lo[j], aA0);
            aA0 = __builtin_elementwise_fma(h0hi, wA_hi[j], aA0);
            aA1 = __builtin_elementwise_fma(h0lo, wB_lo[j], aA1);
            aA1 = __builtin_elementwise_fma(h0hi, wB_hi[j], aA1);
            aB0 = __builtin_elementwise_fma(h1lo, wA_lo[j], aB0);
            aB0 = __builtin_elementwise_fma(h1hi, wA_hi[j], aB0);
            aB1 = __builtin_elementwise_fma(h1lo, wB_lo[j], aB1);
            aB1 = __builtin_elementwise_fma(h1hi, wB_hi[j], aB1);
            float4 g0 = tile4[r0 * 128 + s + 16 * (j + 1)];
            float4 g1 = tile4[r1 * 128 + s + 16 * (j + 1)];
            v2f g0lo = (v2f){g0.x, g0.y}, g0hi = (v2f){g0.z, g0.w};
            v2f g1lo = (v2f){g1.x, g1.y}, g1hi = (v2f){g1.z, g1.w};
            bA0 = __builtin_elementwise_fma(g0lo, wA_lo[j + 1], bA0);
            bA0 = __builtin_elementwise_fma(g0hi, wA_hi[j + 1], bA0);
            bA1 = __builtin_elementwise_fma(g0lo, wB_lo[j + 1], bA1);
            bA1 = __builtin_elementwise_fma(g0hi, wB_hi[j + 1], bA1);
            bB0 = __builtin_elementwise_fma(g1lo, wA_lo[j + 1], bB0);
            bB0 = __builtin_elementwise_fma(g1hi, wA_hi[j + 1], bB0);
            bB1 = __builtin_elementwise_fma(g1lo, wB_lo[j + 1], bB1);
            bB1 = __builtin_elementwise_fma(g1hi, wB_hi[j + 1], bB1);
        }
        v2f sA0 = aA0 + bA0, sA1 = aA1 + bA1, sB0 = aB0 + bB0, sB1 = aB1 + bB1;
        float rA0 = reduce16_add(sA0.x + sA0.y);
        float rA1 = reduce16_add(sA1.x + sA1.y);
        float rB0 = reduce16_add(sB0.x + sB0.y);
        float rB1 = reduce16_add(sB1.x + sB1.y);
        if (s == 0) {
            xp2[(size_t)(row0 + r0) * 16 + g2] = make_float2(rA0 + bias2.x, rA1 + bias2.y);
            xp2[(size_t)(row0 + r1) * 16 + g2] = make_float2(rB0 + bias2.x, rB1 + bias2.y);
        }
    }
}

// ---------------------------------------------------------------------------
// Phase 2: per-batch recurrence. 512 blocks x 256 threads, 1 batch/block,
// __launch_bounds__(256,2) (proven shape: 120 VGPR, no spill). Occupancy is
// grid-capped at 2 blocks/CU; the lever here is critical-path latency:
// round-4 had 25 dependent ds_bpermute round-trips per step (Phase A reduce
// + Phase B scan); this version does both with DPP (VALU latency).
//   A: h-GEMV. g=tid>>4 owns nq {2g,2g+1}; s=tid&15, k=4s+64j. 32 pk-FMA,
//      4-step DPP reduce, float2 qin write. [barrier 1]
//   B: per-wave redundant cos+DPP-cumprod scan; lanes<32 -> sigmoid,
//      lanes>=32 -> tanh; interleaved (sig,th) to per-wave wbuf; in-wave
//      lgkmcnt(0) fence. [no barrier]
//   C: thread owns hid=tid,tid+256: 64 pk-FMA vs broadcast ow, state update,
//      write hbuf + out. [barrier 2]
// ---------------------------------------------------------------------------
__global__ __launch_bounds__(256, 2) void rnn_kernel(const float* __restrict__ xp,
                                                     const float* __restrict__ fc_w,
                                                     const float* __restrict__ out_w,
                                                     const float* __restrict__ out_b,
                                                     float* __restrict__ out) {
    const int b = blockIdx.x;
    const int tid = threadIdx.x;
    const int g = tid >> 4;     // 0..15 : owns nq {2g, 2g+1}
    const int s = tid & 15;     // k lane
    const int w4 = tid >> 6;    // wave id 0..3
    const int lane = tid & 63;
    const int l31 = lane & 31;

    __shared__ __align__(16) float hbuf[2][HID];     // 4 KB double-buffered h
    __shared__ __align__(16) float qin_s[NQ];
    __shared__ __align__(16) float wbuf[4][64];      // per-wave (sig,th) pairs
    __shared__ __align__(16) float xps[SEQ * NQ];    // 32 KB

    // Wh fragments: wh{A,B}_{lo,hi}[j] = fc_w[2g+{0,1}][512 + 4s + 64j + ...]
    v2f whA_lo[8], whA_hi[8], whB_lo[8], whB_hi[8];
    {
        const float* wrA = fc_w + (size_t)(g * 2 + 0) * (IN_DIM + HID) + IN_DIM + 4 * s;
        const float* wrB = fc_w + (size_t)(g * 2 + 1) * (IN_DIM + HID) + IN_DIM + 4 * s;
#pragma unroll
        for (int j = 0; j < 8; ++j) {
            float4 a = *reinterpret_cast<const float4*>(wrA + 64 * j);
            float4 c = *reinterpret_cast<const float4*>(wrB + 64 * j);
            whA_lo[j] = (v2f){a.x, a.y}; whA_hi[j] = (v2f){a.z, a.w};
            whB_lo[j] = (v2f){c.x, c.y}; whB_hi[j] = (v2f){c.z, c.w};
        }
    }
    // out_w rows for hid = tid and tid+256
    float ow0[NQ], ow1[NQ];
    {
        const float4* o0 = reinterpret_cast<const float4*>(out_w + (size_t)tid * NQ);
        const float4* o1 = reinterpret_cast<const float4*>(out_w + (size_t)(tid + 256) * NQ);
#pragma unroll
        for (int q4 = 0; q4 < 8; ++q4) {
            float4 a = o0[q4], bq = o1[q4];
            ow0[4 * q4 + 0] = a.x;  ow0[4 * q4 + 1] = a.y;
            ow0[4 * q4 + 2] = a.z;  ow0[4 * q4 + 3] = a.w;
            ow1[4 * q4 + 0] = bq.x; ow1[4 * q4 + 1] = bq.y;
            ow1[4 * q4 + 2] = bq.z; ow1[4 * q4 + 3] = bq.w;
        }
    }
    const float ob0 = out_b[tid];
    const float ob1 = out_b[tid + 256];

    // stage xp[:, b, :] -> LDS once
    {
        const float4* xpg = reinterpret_cast<const float4*>(xp);
        float4* xps4 = reinterpret_cast<float4*>(xps);
#pragma unroll
        for (int k = 0; k < 8; ++k) {
            int idx = tid + 256 * k;          // 0..2047
            int t = idx >> 3, q4 = idx & 7;
            xps4[idx] = xpg[((size_t)t * BATCH + b) * 8 + q4];
        }
    }
    hbuf[0][tid] = 0.0f;
    hbuf[0][tid + 256] = 0.0f;
    float c0 = 0.0f, c1 = 0.0f;
    __syncthreads();

    float* hx_out = out + (size_t)SEQ * BATCH * HID + (size_t)b * HID;
    float* cx_out = hx_out + (size_t)BATCH * HID;

    int p = 0;
    for (int t = 0; t < SEQ; ++t) {
        // ---- Phase A: q_in = Xp[t,b,:] + h @ Wh.T (pk-FMA + DPP reduce) ---
        const float2 xq = reinterpret_cast<const float2*>(xps)[t * 16 + g];
        const float4* h4 = reinterpret_cast<const float4*>(hbuf[p]);
        v2f aA = (v2f){0.f, 0.f}, aB = aA, bA = aA, bB = aA;  // j-parity split
#pragma unroll
        for (int j = 0; j < 8; j += 2) {
            float4 hv = h4[s + 16 * j];
            v2f hlo = (v2f){hv.x, hv.y}, hhi = (v2f){hv.z, hv.w};
            aA = __builtin_elementwise_fma(hlo, whA_lo[j], aA);
            aA = __builtin_elementwise_fma(hhi, whA_hi[j], aA);
            aB = __builtin_elementwise_fma(hlo, whB_lo[j], aB);
            aB = __builtin_elementwise_fma(hhi, whB_hi[j], aB);
            float4 gv = h4[s + 16 * (j + 1)];
            v2f glo = (v2f){gv.x, gv.y}, ghi = (v2f){gv.z, gv.w};
            bA = __builtin_elementwise_fma(glo, whA_lo[j + 1], bA);
            bA = __builtin_elementwise_fma(ghi, whA_hi[j + 1], bA);
            bB = __builtin_elementwise_fma(glo, whB_lo[j + 1], bB);
            bB = __builtin_elementwise_fma(ghi, whB_hi[j + 1], bB);
        }
        v2f sA = aA + bA, sB = aB + bB;
        float rA = reduce16_add(sA.x + sA.y);
        float rB = reduce16_add(sB.x + sB.y);
        if (s == 0)
            reinterpret_cast<float2*>(qin_s)[g] = make_float2(rA + xq.x, rB + xq.y);
        __syncthreads();                     // barrier 1: qin_s ready

        // ---- Phase B: per-wave redundant DPP scan + activations -----------
        {
            float q = qin_s[l31];
            float pp = scan32_mul(__cosf(q));         // cumprod of cosines
            // pp in [-1,1] -> exp args bounded
            float arg = (lane < 32) ? -pp : (-2.0f * pp);
            float e = __expf(arg);
            float num = (lane < 32) ? 1.0f : (1.0f - e);
            float val = num * fast_rcp(1.0f + e);     // sigmoid | tanh
            wbuf[w4][(l31 << 1) | (lane >> 5)] = val; // sig at 2q, th at 2q+1
        }
        asm volatile("s_waitcnt lgkmcnt(0)" ::: "memory");  // in-wave RAW fence
        __builtin_amdgcn_sched_barrier(0);

        // ---- Phase C: f/g via pk-FMA + state update -----------------------
        const float4* st4 = reinterpret_cast<const float4*>(wbuf[w4]);
        v2f a0 = (v2f){ob0, ob0};            // (f0, g0)
        v2f a1 = (v2f){ob1, ob1};            // (f1, g1)
#pragma unroll
        for (int m = 0; m < 16; ++m) {
            float4 v = st4[m];               // (sig[2m], th[2m], sig[2m+1], th[2m+1])
            v2f plo = (v2f){v.x, v.y}, phi = (v2f){v.z, v.w};
            a0 = __builtin_elementwise_fma(plo, (v2f){ow0[2 * m], ow0[2 * m]}, a0);
            a0 = __builtin_elementwise_fma(phi, (v2f){ow0[2 * m + 1], ow0[2 * m + 1]}, a0);
            a1 = __builtin_elementwise_fma(plo, (v2f){ow1[2 * m], ow1[2 * m]}, a1);
            a1 = __builtin_elementwise_fma(phi, (v2f){ow1[2 * m + 1], ow1[2 * m + 1]}, a1);
        }
        float f0 = a0.x, g0 = a0.y, f1 = a1.x, g1 = a1.y;
        c0 = f0 * (c0 + g0);                 // f*c + i*g with i == f
        c1 = f1 * (c1 + g1);
        float h0 = f0 * tanh_fast(c0);       // o == f
        float h1 = f1 * tanh_fast(c1);

        hbuf[p ^ 1][tid] = h0;
        hbuf[p ^ 1][tid + 256] = h1;
        float* orow = out + ((size_t)t * BATCH + b) * HID;
        orow[tid] = h0;
        orow[tid + 256] = h1;
        if (t == SEQ - 1) {
            hx_out[tid] = h0; hx_out[tid + 256] = h1;
            cx_out[tid] = c0; cx_out[tid + 256] = c1;
        }
        __syncthreads();                     // barrier 2: hbuf[p^1] ready
        p ^= 1;
    }
}

extern "C" void kernel_launch(void* const* d_in, const int* in_sizes, int n_in,
                              void* d_out, int out_size, void* d_ws, size_t ws_size,
                              hipStream_t stream) {
    const float* inputs = (const float*)d_in[0];
    const float* fc_w   = (const float*)d_in[1];
    const float* fc_b   = (const float*)d_in[2];
    const float* out_w  = (const float*)d_in[3];
    const float* out_b  = (const float*)d_in[4];
    float* out = (float*)d_out;
    float* xp  = (float*)d_ws;   // SEQ*BATCH*NQ floats = 16.8 MB

    xp_kernel<<<(SEQ * BATCH) / 16, 256, 0, stream>>>(inputs, fc_w, fc_b, xp);
    rnn_kernel<<<BATCH, 256, 0, stream>>>(xp, fc_w, out_w, out_b, out);
}

// Round 7
// 369.687 us; speedup vs baseline: 1.7694x; 1.0247x over previous
//
#include <hip/hip_runtime.h>
#include <math.h>

#define SEQ 256
#define BATCH 512
#define IN_DIM 512
#define HID 512
#define NQ 32

typedef float v2f __attribute__((ext_vector_type(2)));

__device__ __forceinline__ float fast_rcp(float x) { return __builtin_amdgcn_rcpf(x); }

__device__ __forceinline__ float tanh_fast(float x) {
    // tanh(x) = sign(x) * (1 - e) / (1 + e),  e = exp(-2|x|)  (never overflows)
    float a = fabsf(x);
    float e = __expf(-2.0f * a);
    float r = (1.0f - e) * fast_rcp(1.0f + e);
    return copysignf(r, x);
}

// ---- DPP cross-lane helpers (constant ctrl/mask via templates) -------------
template <int CTRL>
__device__ __forceinline__ float dpp_add(float x) {
    int t = __builtin_amdgcn_update_dpp(0, __float_as_int(x), CTRL, 0xF, 0xF, false);
    return x + __int_as_float(t);
}
// Sum over each 16-lane row (xp_kernel).
__device__ __forceinline__ float reduce16_add(float x) {
    x = dpp_add<0xB1>(x);   // quad_perm [1,0,3,2] : xor1
    x = dpp_add<0x4E>(x);   // quad_perm [2,3,0,1] : xor2
    x = dpp_add<0x141>(x);  // row_half_mirror     : xor4 equivalent
    x = dpp_add<0x140>(x);  // row_mirror          : xor8 equivalent
    return x;
}
// Sum over each 4-lane quad (rnn Phase A).
__device__ __forceinline__ float reduce4_add(float x) {
    x = dpp_add<0xB1>(x);   // xor1
    x = dpp_add<0x4E>(x);   // xor2
    return x;
}
template <int CTRL, int ROW_MASK>
__device__ __forceinline__ float dpp_mul1(float x) {
    int t = __builtin_amdgcn_update_dpp(0x3f800000 /*1.0f*/, __float_as_int(x),
                                        CTRL, ROW_MASK, 0xF, false);
    return x * __int_as_float(t);
}
// Inclusive cumprod within each 32-lane half of the wave.
// bcast15 masked to odd rows (0xA) so lane31 can't leak into the upper half.
__device__ __forceinline__ float scan32_mul(float x) {
    x = dpp_mul1<0x111, 0xF>(x);  // row_shr:1
    x = dpp_mul1<0x112, 0xF>(x);  // row_shr:2
    x = dpp_mul1<0x114, 0xF>(x);  // row_shr:4
    x = dpp_mul1<0x118, 0xF>(x);  // row_shr:8
    x = dpp_mul1<0x142, 0xA>(x);  // row_bcast:15 into odd rows
    return x;
}

// Block barrier WITHOUT vmcnt drain: __syncthreads() emits s_waitcnt vmcnt(0)
// which would stall on Phase C's fire-and-forget global stores every step.
// Only LDS visibility is needed -> lgkmcnt(0) + s_barrier in ONE asm (memory
// clobber keeps the compiler from moving LDS ops across).
#define BLOCK_BARRIER_LDS() asm volatile("s_waitcnt lgkmcnt(0)\n\ts_barrier" ::: "memory")
// Intra-wave LDS RAW fence (producer and consumer in the same wave).
#define WAVE_FENCE_LDS()                                        \
    do {                                                        \
        asm volatile("s_waitcnt lgkmcnt(0)" ::: "memory");      \
        __builtin_amdgcn_sched_barrier(0);                      \
    } while (0)

// ---------------------------------------------------------------------------
// Phase 1: Xp[row][nq] = fc_b[nq] + sum_k inputs[row][k] * fc_w[nq][k]
// Unchanged from round 6 (measured ~61 us).
// ---------------------------------------------------------------------------
__global__ __launch_bounds__(256, 4) void xp_kernel(const float* __restrict__ x,
                                                    const float* __restrict__ fc_w,
                                                    const float* __restrict__ fc_b,
                                                    float* __restrict__ xp) {
    const int tid = threadIdx.x;
    const int g2 = tid >> 4;  // 0..15 : owns nq {2g2, 2g2+1}
    const int s  = tid & 15;  // k lane: k = 4s + 64j

    __shared__ float4 tile4[16 * 128];  // 16 rows x 512 floats = 32 KB

    v2f wA_lo[8], wA_hi[8], wB_lo[8], wB_hi[8];
    {
        const float* wrA = fc_w + (size_t)(g2 * 2 + 0) * (IN_DIM + HID) + 4 * s;
        const float* wrB = fc_w + (size_t)(g2 * 2 + 1) * (IN_DIM + HID) + 4 * s;
#pragma unroll
        for (int j = 0; j < 8; ++j) {
            float4 a = *reinterpret_cast<const float4*>(wrA + 64 * j);
            float4 b = *reinterpret_cast<const float4*>(wrB + 64 * j);
            wA_lo[j] = (v2f){a.x, a.y}; wA_hi[j] = (v2f){a.z, a.w};
            wB_lo[j] = (v2f){b.x, b.y}; wB_hi[j] = (v2f){b.z, b.w};
        }
    }
    const float2 bias2 = reinterpret_cast<const float2*>(fc_b)[g2];

    const float4* x4 = reinterpret_cast<const float4*>(x) + (size_t)blockIdx.x * (16 * 128);
#pragma unroll
    for (int q = 0; q < 8; ++q)
        tile4[tid + 256 * q] = x4[tid + 256 * q];
    __syncthreads();

    const int row0 = blockIdx.x * 16;
    float2* xp2 = reinterpret_cast<float2*>(xp);
    for (int rp = 0; rp < 8; ++rp) {
        const int r0 = 2 * rp, r1 = 2 * rp + 1;
        v2f aA0 = (v2f){0.f, 0.f}, aA1 = aA0, aB0 = aA0, aB1 = aA0;
        v2f bA0 = aA0, bA1 = aA0, bB0 = aA0, bB1 = aA0;  // j-parity split (ILP)
#pragma unroll
        for (int j = 0; j < 8; j += 2) {
            float4 h0 = tile4[r0 * 128 + s + 16 * j];
            float4 h1 = tile4[r1 * 128 + s + 16 * j];
            v2f h0lo = (v2f){h0.x, h0.y}, h0hi = (v2f){h0.z, h0.w};
            v2f h1lo = (v2f){h1.x, h1.y}, h1hi = (v2f){h1.z, h1.w};
            aA0 = __builtin_elementwise_fma(h0lo, wA_lo[j], aA0);
            aA0 = __builtin_elementwise_fma(h0hi, wA_hi[j], aA0);
            aA1 = __builtin_elementwise_fma(h0lo, wB_lo[j], aA1);
            aA1 = __builtin_elementwise_fma(h0hi, wB_hi[j], aA1);
            aB0 = __builtin_elementwise_fma(h1lo, wA_lo[j], aB0);
            aB0 = __builtin_elementwise_fma(h1hi, wA_hi[j], aB0);
            aB1 = __builtin_elementwise_fma(h1lo, wB_lo[j], aB1);
            aB1 = __builtin_elementwise_fma(h1hi, wB_hi[j], aB1);
            float4 g0 = tile4[r0 * 128 + s + 16 * (j + 1)];
            float4 g1 = tile4[r1 * 128 + s + 16 * (j + 1)];
            v2f g0lo = (v2f){g0.x, g0.y}, g0hi = (v2f){g0.z, g0.w};
            v2f g1lo = (v2f){g1.x, g1.y}, g1hi = (v2f){g1.z, g1.w};
            bA0 = __builtin_elementwise_fma(g0lo, wA_lo[j + 1], bA0);
            bA0 = __builtin_elementwise_fma(g0hi, wA_hi[j + 1], bA0);
            bA1 = __builtin_elementwise_fma(g0lo, wB_lo[j + 1], bA1);
            bA1 = __builtin_elementwise_fma(g0hi, wB_hi[j + 1], bA1);
            bB0 = __builtin_elementwise_fma(g1lo, wA_lo[j + 1], bB0);
            bB0 = __builtin_elementwise_fma(g1hi, wA_hi[j + 1], bB0);
            bB1 = __builtin_elementwise_fma(g1lo, wB_lo[j + 1], bB1);
            bB1 = __builtin_elementwise_fma(g1hi, wB_hi[j + 1], bB1);
        }
        v2f sA0 = aA0 + bA0, sA1 = aA1 + bA1, sB0 = aB0 + bB0, sB1 = aB1 + bB1;
        float rA0 = reduce16_add(sA0.x + sA0.y);
        float rA1 = reduce16_add(sA1.x + sA1.y);
        float rB0 = reduce16_add(sB0.x + sB0.y);
        float rB1 = reduce16_add(sB1.x + sB1.y);
        if (s == 0) {
            xp2[(size_t)(row0 + r0) * 16 + g2] = make_float2(rA0 + bias2.x, rA1 + bias2.y);
            xp2[(size_t)(row0 + r1) * 16 + g2] = make_float2(rB0 + bias2.x, rB1 + bias2.y);
        }
    }
}

// ---------------------------------------------------------------------------
// Phase 2: per-batch recurrence, ONE block barrier per step.
// 512 blocks x 256 threads, __launch_bounds__(256,2).
// Wave w owns hid slice [128w, 128w+128): it WRITES h for that slice in
// Phase C and REDUCES over the same slice as its k-range in Phase A -> the
// h-write->h-read edge is intra-wave (lgkmcnt fence, no barrier). Only the
// 4 per-wave qin partials cross waves -> one barrier, pbuf double-buffered
// by step parity (wave skew across the single barrier is at most one phase).
//   A: grp=lane>>2 owns nq {2grp,2grp+1}; sl=lane&3 covers k=128w+32sl+[0,32).
//      8 broadcast-4 LDS float4 reads, 32 pk-FMA, 2-step DPP quad reduce,
//      float2 partial write to pbuf[par][w].           [BLOCK_BARRIER_LDS]
//   B: qin = sum of 4 partials (broadcast b32 reads) + xps -> in-register;
//      cos+DPP-cumprod scan; lanes<32 sigmoid, lanes>=32 tanh; interleaved
//      (sig,th) pairs to per-wave wbuf.                [WAVE_FENCE_LDS]
//   C: lane owns hid 128w+lane and 128w+64+lane; 64 pk-FMA vs broadcast
//      wbuf pairs; state update; write hbuf slice + out (stores never
//      drained in-loop -- raw barrier skips vmcnt).    [WAVE_FENCE_LDS]
// ---------------------------------------------------------------------------
__global__ __launch_bounds__(256, 2) void rnn_kernel(const float* __restrict__ xp,
                                                     const float* __restrict__ fc_w,
                                                     const float* __restrict__ out_w,
                                                     const float* __restrict__ out_b,
                                                     float* __restrict__ out) {
    const int b = blockIdx.x;
    const int tid = threadIdx.x;
    const int w4 = tid >> 6;    // wave id 0..3 : owns hid [128w4, 128w4+128)
    const int lane = tid & 63;
    const int l31 = lane & 31;
    const int grp = lane >> 2;  // 0..15 : owns nq {2grp, 2grp+1}
    const int sl = lane & 3;    // k sub-slice within the wave's 128-range

    __shared__ __align__(16) float hbuf[HID];        // 2 KB (single buffer)
    __shared__ __align__(16) float pbuf[2][4][NQ];   // 1 KB  qin partials
    __shared__ __align__(16) float wbuf[4][64];      // 1 KB  (sig,th) pairs
    __shared__ __align__(16) float xps[SEQ * NQ];    // 32 KB

    // Phase-A weights: k = 128*w4 + 32*sl + [0,32)  (8 consecutive float4)
    v2f whA_lo[8], whA_hi[8], whB_lo[8], whB_hi[8];
    {
        const int kbase = IN_DIM + 128 * w4 + 32 * sl;
        const float* wrA = fc_w + (size_t)(grp * 2 + 0) * (IN_DIM + HID) + kbase;
        const float* wrB = fc_w + (size_t)(grp * 2 + 1) * (IN_DIM + HID) + kbase;
#pragma unroll
        for (int j = 0; j < 8; ++j) {
            float4 a = *reinterpret_cast<const float4*>(wrA + 4 * j);
            float4 c = *reinterpret_cast<const float4*>(wrB + 4 * j);
            whA_lo[j] = (v2f){a.x, a.y}; whA_hi[j] = (v2f){a.z, a.w};
            whB_lo[j] = (v2f){c.x, c.y}; whB_hi[j] = (v2f){c.z, c.w};
        }
    }
    // Phase-C rows: hid0 = 128*w4 + lane, hid1 = hid0 + 64
    const int hid0 = 128 * w4 + lane;
    const int hid1 = hid0 + 64;
    float ow0[NQ], ow1[NQ];
    {
        const float4* o0 = reinterpret_cast<const float4*>(out_w + (size_t)hid0 * NQ);
        const float4* o1 = reinterpret_cast<const float4*>(out_w + (size_t)hid1 * NQ);
#pragma unroll
        for (int q4 = 0; q4 < 8; ++q4) {
            float4 a = o0[q4], bq = o1[q4];
            ow0[4 * q4 + 0] = a.x;  ow0[4 * q4 + 1] = a.y;
            ow0[4 * q4 + 2] = a.z;  ow0[4 * q4 + 3] = a.w;
            ow1[4 * q4 + 0] = bq.x; ow1[4 * q4 + 1] = bq.y;
            ow1[4 * q4 + 2] = bq.z; ow1[4 * q4 + 3] = bq.w;
        }
    }
    const float ob0 = out_b[hid0];
    const float ob1 = out_b[hid1];

    // stage xp[:, b, :] -> LDS once
    {
        const float4* xpg = reinterpret_cast<const float4*>(xp);
        float4* xps4 = reinterpret_cast<float4*>(xps);
#pragma unroll
        for (int k = 0; k < 8; ++k) {
            int idx = tid + 256 * k;          // 0..2047
            int t = idx >> 3, q4 = idx & 7;
            xps4[idx] = xpg[((size_t)t * BATCH + b) * 8 + q4];
        }
    }
    hbuf[tid] = 0.0f;
    hbuf[tid + 256] = 0.0f;
    float c0 = 0.0f, c1 = 0.0f;
    __syncthreads();   // once, outside the loop (init visibility)

    float* hx_out = out + (size_t)SEQ * BATCH * HID + (size_t)b * HID;
    float* cx_out = hx_out + (size_t)BATCH * HID;

    const float4* h4 = reinterpret_cast<const float4*>(hbuf) + (32 * w4 + 8 * sl);

    int par = 0;
    for (int t = 0; t < SEQ; ++t) {
        // ---- Phase A: partial q_in over the wave's own 128-k slice --------
        v2f aA = (v2f){0.f, 0.f}, aB = aA, bA = aA, bB = aA;  // j-parity ILP
#pragma unroll
        for (int j = 0; j < 8; j += 2) {
            float4 hv = h4[j];
            v2f hlo = (v2f){hv.x, hv.y}, hhi = (v2f){hv.z, hv.w};
            aA = __builtin_elementwise_fma(hlo, whA_lo[j], aA);
            aA = __builtin_elementwise_fma(hhi, whA_hi[j], aA);
            aB = __builtin_elementwise_fma(hlo, whB_lo[j], aB);
            aB = __builtin_elementwise_fma(hhi, whB_hi[j], aB);
            float4 gv = h4[j + 1];
            v2f glo = (v2f){gv.x, gv.y}, ghi = (v2f){gv.z, gv.w};
            bA = __builtin_elementwise_fma(glo, whA_lo[j + 1], bA);
            bA = __builtin_elementwise_fma(ghi, whA_hi[j + 1], bA);
            bB = __builtin_elementwise_fma(glo, whB_lo[j + 1], bB);
            bB = __builtin_elementwise_fma(ghi, whB_hi[j + 1], bB);
        }
        v2f sA = aA + bA, sB = aB + bB;
        float rA = reduce4_add(sA.x + sA.y);
        float rB = reduce4_add(sB.x + sB.y);
        if (sl == 0)
            *reinterpret_cast<float2*>(&pbuf[par][w4][2 * grp]) = make_float2(rA, rB);

        BLOCK_BARRIER_LDS();                 // the ONE barrier per step

        // ---- Phase B: combine partials (in-register) + scan + activations -
        {
            const float* pb = &pbuf[par][0][0];
            float qin = (pb[l31] + pb[32 + l31]) + (pb[64 + l31] + pb[96 + l31])
                      + xps[t * NQ + l31];
            float pp = scan32_mul(__cosf(qin));       // cumprod of cosines
            float arg = (lane < 32) ? -pp : (-2.0f * pp);   // pp in [-1,1]
            float e = __expf(arg);
            float num = (lane < 32) ? 1.0f : (1.0f - e);
            float val = num * fast_rcp(1.0f + e);     // sigmoid | tanh
            wbuf[w4][(l31 << 1) | (lane >> 5)] = val; // sig at 2q, th at 2q+1
        }
        WAVE_FENCE_LDS();                    // wbuf RAW (same wave)

        // ---- Phase C: f/g via pk-FMA + state update -----------------------
        const float4* st4 = reinterpret_cast<const float4*>(wbuf[w4]);
        v2f a0 = (v2f){ob0, ob0};            // (f0, g0)
        v2f a1 = (v2f){ob1, ob1};            // (f1, g1)
#pragma unroll
        for (int m = 0; m < 16; ++m) {
            float4 v = st4[m];               // (sig[2m], th[2m], sig[2m+1], th[2m+1])
            v2f plo = (v2f){v.x, v.y}, phi = (v2f){v.z, v.w};
            a0 = __builtin_elementwise_fma(plo, (v2f){ow0[2 * m], ow0[2 * m]}, a0);
            a0 = __builtin_elementwise_fma(phi, (v2f){ow0[2 * m + 1], ow0[2 * m + 1]}, a0);
            a1 = __builtin_elementwise_fma(plo, (v2f){ow1[2 * m], ow1[2 * m]}, a1);
            a1 = __builtin_elementwise_fma(phi, (v2f){ow1[2 * m + 1], ow1[2 * m + 1]}, a1);
        }
        float f0 = a0.x, g0 = a0.y, f1 = a1.x, g1 = a1.y;
        c0 = f0 * (c0 + g0);                 // f*c + i*g with i == f
        c1 = f1 * (c1 + g1);
        float h0 = f0 * tanh_fast(c0);       // o == f
        float h1 = f1 * tanh_fast(c1);

        hbuf[hid0] = h0;
        hbuf[hid1] = h1;
        float* orow = out + ((size_t)t * BATCH + b) * HID;
        orow[hid0] = h0;
        orow[hid1] = h1;
        if (t == SEQ - 1) {
            hx_out[hid0] = h0; hx_out[hid1] = h1;
            cx_out[hid0] = c0; cx_out[hid1] = c1;
        }
        WAVE_FENCE_LDS();                    // hbuf RAW (same wave, next A)
        par ^= 1;
    }
}

extern "C" void kernel_launch(void* const* d_in, const int* in_sizes, int n_in,
                              void* d_out, int out_size, void* d_ws, size_t ws_size,
                              hipStream_t stream) {
    const float* inputs = (const float*)d_in[0];
    const float* fc_w   = (const float*)d_in[1];
    const float* fc_b   = (const float*)d_in[2];
    const float* out_w  = (const float*)d_in[3];
    const float* out_b  = (const float*)d_in[4];
    float* out = (float*)d_out;
    float* xp  = (float*)d_ws;   // SEQ*BATCH*NQ floats = 16.8 MB

    xp_kernel<<<(SEQ * BATCH) / 16, 256, 0, stream>>>(inputs, fc_w, fc_b, xp);
    rnn_kernel<<<BATCH, 256, 0, stream>>>(xp, fc_w, out_w, out_b, out);
}

// Round 8
// 365.192 us; speedup vs baseline: 1.7912x; 1.0123x over previous
//
#include <hip/hip_runtime.h>
#include <math.h>

#define SEQ 256
#define BATCH 512
#define IN_DIM 512
#define HID 512
#define NQ 32

typedef float v2f __attribute__((ext_vector_type(2)));

__device__ __forceinline__ float fast_rcp(float x) { return __builtin_amdgcn_rcpf(x); }

__device__ __forceinline__ float tanh_fast(float x) {
    // tanh(x) = sign(x) * (1 - e) / (1 + e),  e = exp(-2|x|)  (never overflows)
    float a = fabsf(x);
    float e = __expf(-2.0f * a);
    float r = (1.0f - e) * fast_rcp(1.0f + e);
    return copysignf(r, x);
}

// ---- DPP cross-lane helpers (constant ctrl/mask via templates) -------------
template <int CTRL>
__device__ __forceinline__ float dpp_add(float x) {
    int t = __builtin_amdgcn_update_dpp(0, __float_as_int(x), CTRL, 0xF, 0xF, false);
    return x + __int_as_float(t);
}
// Sum over each 16-lane row (xp_kernel).
__device__ __forceinline__ float reduce16_add(float x) {
    x = dpp_add<0xB1>(x);   // quad_perm [1,0,3,2] : xor1
    x = dpp_add<0x4E>(x);   // quad_perm [2,3,0,1] : xor2
    x = dpp_add<0x141>(x);  // row_half_mirror     : xor4 equivalent
    x = dpp_add<0x140>(x);  // row_mirror          : xor8 equivalent
    return x;
}
// Sum over each 4-lane quad (rnn Phase A).
__device__ __forceinline__ float reduce4_add(float x) {
    x = dpp_add<0xB1>(x);   // xor1
    x = dpp_add<0x4E>(x);   // xor2
    return x;
}
template <int CTRL, int ROW_MASK>
__device__ __forceinline__ float dpp_mul1(float x) {
    int t = __builtin_amdgcn_update_dpp(0x3f800000 /*1.0f*/, __float_as_int(x),
                                        CTRL, ROW_MASK, 0xF, false);
    return x * __int_as_float(t);
}
// Inclusive cumprod within each 32-lane half of the wave.
// bcast15 masked to odd rows (0xA) so lane31 can't leak into the upper half.
__device__ __forceinline__ float scan32_mul(float x) {
    x = dpp_mul1<0x111, 0xF>(x);  // row_shr:1
    x = dpp_mul1<0x112, 0xF>(x);  // row_shr:2
    x = dpp_mul1<0x114, 0xF>(x);  // row_shr:4
    x = dpp_mul1<0x118, 0xF>(x);  // row_shr:8
    x = dpp_mul1<0x142, 0xA>(x);  // row_bcast:15 into odd rows
    return x;
}

// Block barrier WITHOUT vmcnt drain (__syncthreads would wait on Phase C's
// fire-and-forget global stores). LDS visibility only: lgkmcnt(0)+s_barrier.
// The "memory" clobber pins all LDS ops on their side of the barrier; within
// a wave, DS ops execute in order, so wave-private LDS needs no extra fence.
#define BLOCK_BARRIER_LDS() asm volatile("s_waitcnt lgkmcnt(0)\n\ts_barrier" ::: "memory")

// ---------------------------------------------------------------------------
// Phase 1: Xp[row][nq] = fc_b[nq] + sum_k inputs[row][k] * fc_w[nq][k]
// Unchanged from round 6/7 (measured ~61 us).
// ---------------------------------------------------------------------------
__global__ __launch_bounds__(256, 4) void xp_kernel(const float* __restrict__ x,
                                                    const float* __restrict__ fc_w,
                                                    const float* __restrict__ fc_b,
                                                    float* __restrict__ xp) {
    const int tid = threadIdx.x;
    const int g2 = tid >> 4;  // 0..15 : owns nq {2g2, 2g2+1}
    const int s  = tid & 15;  // k lane: k = 4s + 64j

    __shared__ float4 tile4[16 * 128];  // 16 rows x 512 floats = 32 KB

    v2f wA_lo[8], wA_hi[8], wB_lo[8], wB_hi[8];
    {
        const float* wrA = fc_w + (size_t)(g2 * 2 + 0) * (IN_DIM + HID) + 4 * s;
        const float* wrB = fc_w + (size_t)(g2 * 2 + 1) * (IN_DIM + HID) + 4 * s;
#pragma unroll
        for (int j = 0; j < 8; ++j) {
            float4 a = *reinterpret_cast<const float4*>(wrA + 64 * j);
            float4 b = *reinterpret_cast<const float4*>(wrB + 64 * j);
            wA_lo[j] = (v2f){a.x, a.y}; wA_hi[j] = (v2f){a.z, a.w};
            wB_lo[j] = (v2f){b.x, b.y}; wB_hi[j] = (v2f){b.z, b.w};
        }
    }
    const float2 bias2 = reinterpret_cast<const float2*>(fc_b)[g2];

    const float4* x4 = reinterpret_cast<const float4*>(x) + (size_t)blockIdx.x * (16 * 128);
#pragma unroll
    for (int q = 0; q < 8; ++q)
        tile4[tid + 256 * q] = x4[tid + 256 * q];
    __syncthreads();

    const int row0 = blockIdx.x * 16;
    float2* xp2 = reinterpret_cast<float2*>(xp);
    for (int rp = 0; rp < 8; ++rp) {
        const int r0 = 2 * rp, r1 = 2 * rp + 1;
        v2f aA0 = (v2f){0.f, 0.f}, aA1 = aA0, aB0 = aA0, aB1 = aA0;
        v2f bA0 = aA0, bA1 = aA0, bB0 = aA0, bB1 = aA0;  // j-parity split (ILP)
#pragma unroll
        for (int j = 0; j < 8; j += 2) {
            float4 h0 = tile4[r0 * 128 + s + 16 * j];
            float4 h1 = tile4[r1 * 128 + s + 16 * j];
            v2f h0lo = (v2f){h0.x, h0.y}, h0hi = (v2f){h0.z, h0.w};
            v2f h1lo = (v2f){h1.x, h1.y}, h1hi = (v2f){h1.z, h1.w};
            aA0 = __builtin_elementwise_fma(h0lo, wA_lo[j], aA0);
            aA0 = __builtin_elementwise_fma(h0hi, wA_hi[j], aA0);
            aA1 = __builtin_elementwise_fma(h0lo, wB_lo[j], aA1);
            aA1 = __builtin_elementwise_fma(h0hi, wB_hi[j], aA1);
            aB0 = __builtin_elementwise_fma(h1lo, wA_lo[j], aB0);
            aB0 = __builtin_elementwise_fma(h1hi, wA_hi[j], aB0);
            aB1 = __builtin_elementwise_fma(h1lo, wB_lo[j], aB1);
            aB1 = __builtin_elementwise_fma(h1hi, wB_hi[j], aB1);
            float4 g0 = tile4[r0 * 128 + s + 16 * (j + 1)];
            float4 g1 = tile4[r1 * 128 + s + 16 * (j + 1)];
            v2f g0lo = (v2f){g0.x, g0.y}, g0hi = (v2f){g0.z, g0.w};
            v2f g1lo = (v2f){g1.x, g1.y}, g1hi = (v2f){g1.z, g1.w};
            bA0 = __builtin_elementwise_fma(g0lo, wA_lo[j + 1], bA0);
            bA0 = __builtin_elementwise_fma(g0hi, wA_hi[j + 1], bA0);
            bA1 = __builtin_elementwise_fma(g0lo, wB_lo[j + 1], bA1);
            bA1 = __builtin_elementwise_fma(g0hi, wB_hi[j + 1], bA1);
            bB0 = __builtin_elementwise_fma(g1lo, wA_lo[j + 1], bB0);
            bB0 = __builtin_elementwise_fma(g1hi, wA_hi[j + 1], bB0);
            bB1 = __builtin_elementwise_fma(g1lo, wB_lo[j + 1], bB1);
            bB1 = __builtin_elementwise_fma(g1hi, wB_hi[j + 1], bB1);
        }
        v2f sA0 = aA0 + bA0, sA1 = aA1 + bA1, sB0 = aB0 + bB0, sB1 = aB1 + bB1;
        float rA0 = reduce16_add(sA0.x + sA0.y);
        float rA1 = reduce16_add(sA1.x + sA1.y);
        float rB0 = reduce16_add(sB0.x + sB0.y);
        float rB1 = reduce16_add(sB1.x + sB1.y);
        if (s == 0) {
            xp2[(size_t)(row0 + r0) * 16 + g2] = make_float2(rA0 + bias2.x, rA1 + bias2.y);
            xp2[(size_t)(row0 + r1) * 16 + g2] = make_float2(rB0 + bias2.x, rB1 + bias2.y);
        }
    }
}

// ---------------------------------------------------------------------------
// Phase 2: per-batch recurrence, one block barrier + zero wave fences per step.
// 512 blocks x 256 threads. amdgpu_waves_per_eu(2,2) pins the register budget
// to 256 VGPR (rounds 6/7 reported VGPR=116 with ~128 floats of live weights
// -> compiler was squeezing for occupancy and spilling to scratch).
// Wave w owns hid slice [128w,128w+128): writes h there (Phase C) and reduces
// over it as its k-range (Phase A) -> h edges are wave-private (in-order DS,
// no fence). Only qin partials cross waves (pbuf, parity double-buffered).
//   A: grp=lane>>2 owns nq {2grp,2grp+1}; sl=lane&3; k = 128w4+16j+4sl+[0,4)
//      (sl interleaved at float4 grain -> banks (4sl+16j)%32 distinct: no
//      conflict; round-7's 128B-spaced layout was a 4-way conflict).
//      8 b128 reads (static offsets), 32 pk-FMA, 2-step DPP quad reduce.
//   B: qin = 4 partials + xps (broadcast b32) -> cos -> DPP cumprod scan;
//      lanes<32 sigmoid -> pwbuf[w][q], lanes>=32 tanh -> pwbuf[w][32+q].
//   C: lane owns hid 128w+lane, +64: 64 pk-FMA over q-PAIRS with natural
//      (sig,sig)/(th,th) float2 operands vs ow v2f pairs -- no broadcast
//      movs (round-7 built (x,x) pairs per FMA).
// ---------------------------------------------------------------------------
__global__ __launch_bounds__(256)
__attribute__((amdgpu_waves_per_eu(2, 2)))
void rnn_kernel(const float* __restrict__ xp,
                const float* __restrict__ fc_w,
                const float* __restrict__ out_w,
                const float* __restrict__ out_b,
                float* __restrict__ out) {
    const int b = blockIdx.x;
    const int tid = threadIdx.x;
    const int w4 = tid >> 6;    // wave id 0..3 : owns hid [128w4, 128w4+128)
    const int lane = tid & 63;
    const int l31 = lane & 31;
    const int grp = lane >> 2;  // 0..15 : owns nq {2grp, 2grp+1}
    const int sl = lane & 3;    // k sub-slice (float4-interleaved)

    __shared__ __align__(16) float hbuf[HID];        // 2 KB, wave-private slices
    __shared__ __align__(16) float pbuf[2][4][NQ];   // 1 KB, qin partials
    __shared__ __align__(16) float pwbuf[4][64];     // 1 KB, sig[32]|tanh[32]
    __shared__ __align__(16) float xps[SEQ * NQ];    // 32 KB

    // Phase-A weights: k = 128*w4 + 16*j + 4*sl + {0..3}, j = 0..7
    v2f whA_lo[8], whA_hi[8], whB_lo[8], whB_hi[8];
    {
        const int kbase = IN_DIM + 128 * w4 + 4 * sl;
        const float* wrA = fc_w + (size_t)(grp * 2 + 0) * (IN_DIM + HID) + kbase;
        const float* wrB = fc_w + (size_t)(grp * 2 + 1) * (IN_DIM + HID) + kbase;
#pragma unroll
        for (int j = 0; j < 8; ++j) {
            float4 a = *reinterpret_cast<const float4*>(wrA + 16 * j);
            float4 c = *reinterpret_cast<const float4*>(wrB + 16 * j);
            whA_lo[j] = (v2f){a.x, a.y}; whA_hi[j] = (v2f){a.z, a.w};
            whB_lo[j] = (v2f){c.x, c.y}; whB_hi[j] = (v2f){c.z, c.w};
        }
    }
    // Phase-C rows as v2f pairs: hid0 = 128*w4 + lane, hid1 = hid0 + 64
    const int hid0 = 128 * w4 + lane;
    const int hid1 = hid0 + 64;
    v2f ow0v[16], ow1v[16];
    {
        const float4* o0 = reinterpret_cast<const float4*>(out_w + (size_t)hid0 * NQ);
        const float4* o1 = reinterpret_cast<const float4*>(out_w + (size_t)hid1 * NQ);
#pragma unroll
        for (int q4 = 0; q4 < 8; ++q4) {
            float4 a = o0[q4], bq = o1[q4];
            ow0v[2 * q4 + 0] = (v2f){a.x, a.y};
            ow0v[2 * q4 + 1] = (v2f){a.z, a.w};
            ow1v[2 * q4 + 0] = (v2f){bq.x, bq.y};
            ow1v[2 * q4 + 1] = (v2f){bq.z, bq.w};
        }
    }
    const float ob0 = out_b[hid0];
    const float ob1 = out_b[hid1];

    // stage xp[:, b, :] -> LDS once
    {
        const float4* xpg = reinterpret_cast<const float4*>(xp);
        float4* xps4 = reinterpret_cast<float4*>(xps);
#pragma unroll
        for (int k = 0; k < 8; ++k) {
            int idx = tid + 256 * k;          // 0..2047
            int t = idx >> 3, q4 = idx & 7;
            xps4[idx] = xpg[((size_t)t * BATCH + b) * 8 + q4];
        }
    }
    hbuf[tid] = 0.0f;
    hbuf[tid + 256] = 0.0f;
    float c0 = 0.0f, c1 = 0.0f;
    __syncthreads();   // once, outside the loop (init visibility)

    float* hx_out = out + (size_t)SEQ * BATCH * HID + (size_t)b * HID;
    float* cx_out = hx_out + (size_t)BATCH * HID;

    // h float4 base for Phase A: idx = 32*w4 + sl + 4*j  (static offsets 4j)
    const float4* h4s = reinterpret_cast<const float4*>(hbuf) + (32 * w4 + sl);

    int par = 0;
    for (int t = 0; t < SEQ; ++t) {
        // ---- Phase A: partial q_in over the wave's own 128-k slice --------
        v2f aA = (v2f){0.f, 0.f}, aB = aA, bA = aA, bB = aA;  // j-parity ILP
#pragma unroll
        for (int j = 0; j < 8; j += 2) {
            float4 hv = h4s[4 * j];
            v2f hlo = (v2f){hv.x, hv.y}, hhi = (v2f){hv.z, hv.w};
            aA = __builtin_elementwise_fma(hlo, whA_lo[j], aA);
            aA = __builtin_elementwise_fma(hhi, whA_hi[j], aA);
            aB = __builtin_elementwise_fma(hlo, whB_lo[j], aB);
            aB = __builtin_elementwise_fma(hhi, whB_hi[j], aB);
            float4 gv = h4s[4 * (j + 1)];
            v2f glo = (v2f){gv.x, gv.y}, ghi = (v2f){gv.z, gv.w};
            bA = __builtin_elementwise_fma(glo, whA_lo[j + 1], bA);
            bA = __builtin_elementwise_fma(ghi, whA_hi[j + 1], bA);
            bB = __builtin_elementwise_fma(glo, whB_lo[j + 1], bB);
            bB = __builtin_elementwise_fma(ghi, whB_hi[j + 1], bB);
        }
        v2f sA = aA + bA, sB = aB + bB;
        float rA = reduce4_add(sA.x + sA.y);
        float rB = reduce4_add(sB.x + sB.y);
        if (sl == 0)
            *reinterpret_cast<float2*>(&pbuf[par][w4][2 * grp]) = make_float2(rA, rB);

        BLOCK_BARRIER_LDS();                 // the ONE barrier per step

        // ---- Phase B: combine partials + scan + activations ---------------
        {
            const float* pb = &pbuf[par][0][0];
            float qin = (pb[l31] + pb[32 + l31]) + (pb[64 + l31] + pb[96 + l31])
                      + xps[t * NQ + l31];
            float pp = scan32_mul(__cosf(qin));       // cumprod of cosines
            float arg = (lane < 32) ? -pp : (-2.0f * pp);   // pp in [-1,1]
            float e = __expf(arg);
            float num = (lane < 32) ? 1.0f : (1.0f - e);
            float val = num * fast_rcp(1.0f + e);     // sigmoid | tanh
            pwbuf[w4][lane] = val;  // sig at [0..31], tanh at [32..63]
        }
        // (no fence: pwbuf is wave-private; DS ops are in-order per wave)

        // ---- Phase C: f/g via q-pair pk-FMA + state update ----------------
        const float4* sb4 = reinterpret_cast<const float4*>(&pwbuf[w4][0]);   // sig
        const float4* tb4 = sb4 + 8;                                          // tanh
        v2f f0a = (v2f){0.f, 0.f}, f0b = f0a, g0a = f0a, g0b = f0a;
        v2f f1a = f0a, f1b = f0a, g1a = f0a, g1b = f0a;
#pragma unroll
        for (int m = 0; m < 8; ++m) {
            float4 sv = sb4[m];               // sig[4m .. 4m+3]
            float4 tv = tb4[m];               // tanh[4m .. 4m+3]
            v2f slo = (v2f){sv.x, sv.y}, shi = (v2f){sv.z, sv.w};
            v2f tlo = (v2f){tv.x, tv.y}, thi = (v2f){tv.z, tv.w};
            f0a = __builtin_elementwise_fma(slo, ow0v[2 * m + 0], f0a);
            f0b = __builtin_elementwise_fma(shi, ow0v[2 * m + 1], f0b);
            g0a = __builtin_elementwise_fma(tlo, ow0v[2 * m + 0], g0a);
            g0b = __builtin_elementwise_fma(thi, ow0v[2 * m + 1], g0b);
            f1a = __builtin_elementwise_fma(slo, ow1v[2 * m + 0], f1a);
            f1b = __builtin_elementwise_fma(shi, ow1v[2 * m + 1], f1b);
            g1a = __builtin_elementwise_fma(tlo, ow1v[2 * m + 0], g1a);
            g1b = __builtin_elementwise_fma(thi, ow1v[2 * m + 1], g1b);
        }
        v2f sf0 = f0a + f0b, sg0 = g0a + g0b, sf1 = f1a + f1b, sg1 = g1a + g1b;
        float f0 = ob0 + sf0.x + sf0.y, g0 = ob0 + sg0.x + sg0.y;
        float f1 = ob1 + sf1.x + sf1.y, g1 = ob1 + sg1.x + sg1.y;
        c0 = f0 * (c0 + g0);                 // f*c + i*g with i == f
        c1 = f1 * (c1 + g1);
        float h0 = f0 * tanh_fast(c0);       // o == f
        float h1 = f1 * tanh_fast(c1);

        hbuf[hid0] = h0;                     // wave-private slice
        hbuf[hid1] = h1;
        float* orow = out + ((size_t)t * BATCH + b) * HID;
        orow[hid0] = h0;
        orow[hid1] = h1;
        if (t == SEQ - 1) {
            hx_out[hid0] = h0; hx_out[hid1] = h1;
            cx_out[hid0] = c0; cx_out[hid1] = c1;
        }
        // (no fence: next Phase A reads only this wave's hbuf slice)
        par ^= 1;
    }
}

extern "C" void kernel_launch(void* const* d_in, const int* in_sizes, int n_in,
                              void* d_out, int out_size, void* d_ws, size_t ws_size,
                              hipStream_t stream) {
    const float* inputs = (const float*)d_in[0];
    const float* fc_w   = (const float*)d_in[1];
    const float* fc_b   = (const float*)d_in[2];
    const float* out_w  = (const float*)d_in[3];
    const float* out_b  = (const float*)d_in[4];
    float* out = (float*)d_out;
    float* xp  = (float*)d_ws;   // SEQ*BATCH*NQ floats = 16.8 MB

    xp_kernel<<<(SEQ * BATCH) / 16, 256, 0, stream>>>(inputs, fc_w, fc_b, xp);
    rnn_kernel<<<BATCH, 256, 0, stream>>>(xp, fc_w, out_w, out_b, out);
}